// Round 9
// baseline (130.353 us; speedup 1.0000x reference)
//
#include <hip/hip_runtime.h>

typedef _Float16 f16;
typedef unsigned short u16;
typedef __attribute__((ext_vector_type(8))) f16 f16x8;
typedef __attribute__((ext_vector_type(4))) f16 f16x4;
typedef __attribute__((ext_vector_type(4))) float floatx4;
typedef __attribute__((ext_vector_type(2))) __fp16 h2;   // builtin half type

union pk4 { h2 h[2]; f16x4 v; };   // cvt_pkrtz pairs <-> MFMA A-frag

#define NPIX 4096
#define KT   128          // keys per attention tile
#define NT   (NPIX / KT)  // 32 key tiles
#define VROW 136          // padded V LDS row (128 keys + 8) in f16

// ---------------------------------------------------------------------------
// Kernel 0: X transpose+convert, ONCE: [b][c][p] fp32 -> XT [b][p][c] f16.
// qkv re-reads X with 6-fold redundancy as channel-consecutive fragments;
// doing the transpose+f16 convert once turns qkv's 32 scalar gathers/lane
// into 4 coalesced f16x8 loads. grid (256 p-tiles of 16, 4 b) = 1024 blocks
// (4/CU), LDS 4.3 KB/block, both global sides fully coalesced.
// ---------------------------------------------------------------------------
__global__ __launch_bounds__(256) void xpose(
    const float* __restrict__ x, f16* __restrict__ xt)
{
    __shared__ f16 t[16 * 136];        // [p][c] padded
    const int tid = threadIdx.x;
    const int pbase = blockIdx.x * 16;
    const int b = blockIdx.y;
    const float* xb = x + (size_t)b * 128 * NPIX;

#pragma unroll
    for (int i = 0; i < 2; ++i) {
        int idx = i * 256 + tid;               // 512 float4 = 128 c x 16 p
        int c = idx >> 2, p4 = (idx & 3) * 4;
        float4 v = *(const float4*)(xb + (size_t)c * NPIX + pbase + p4);
        t[(p4 + 0) * 136 + c] = (f16)v.x;
        t[(p4 + 1) * 136 + c] = (f16)v.y;
        t[(p4 + 2) * 136 + c] = (f16)v.z;
        t[(p4 + 3) * 136 + c] = (f16)v.w;
    }
    __syncthreads();

    f16* ob = xt + ((size_t)b * NPIX + pbase) * 128;
    {
        int p = tid >> 4, c8 = (tid & 15) * 8; // 256 f16x8 = 16 p x 128 c
        *(f16x8*)(ob + (size_t)p * 128 + c8) = *(const f16x8*)&t[p * 136 + c8];
    }
}

// ---------------------------------------------------------------------------
// Kernel 1: QKV projection as fp16 MFMA GEMM.
// v9: X fragments now 4 coalesced f16x8 loads from XT (was 32 scalar fp32
// gathers at stride NPIX). Both branches consume the same X fragment.
// W staging, MFMA structure, and all stores unchanged.
// grid (64 p-tiles, 6 o-tiles of 64, 4 b), block 256 (4 waves).
// ---------------------------------------------------------------------------
__global__ __launch_bounds__(256) void qkv_mfma(
    const f16* __restrict__ xt, const float* __restrict__ w,
    f16* __restrict__ qh, f16* __restrict__ kh, f16* __restrict__ vth)
{
    __shared__ f16 wlds[64 * 136];     // [o][c] padded (+8) -> conflict-free frags
    const int tid  = threadIdx.x;
    const int wave = tid >> 6;
    const int lane = tid & 63;
    const int quad = lane >> 4;
    const int l16  = lane & 15;
    const int pbase = blockIdx.x * 64;
    const int y     = blockIdx.y;      // o-tile of 64; type = y>>1
    const int b     = blockIdx.z;

#pragma unroll
    for (int i = 0; i < 8; ++i) {
        int idx = i * 256 + tid;               // 2048 float4
        int o = idx >> 5, ch = idx & 31;
        float4 wv = *(const float4*)(w + (size_t)(y * 64 + o) * 128 + ch * 4);
        f16x4 h; h[0] = (f16)wv.x; h[1] = (f16)wv.y; h[2] = (f16)wv.z; h[3] = (f16)wv.w;
        *(f16x4*)&wlds[o * 136 + ch * 4] = h;
    }
    __syncthreads();

    const int type = y >> 1;                   // 0=q 1=k 2=v
    const int p_row = pbase + wave * 16 + l16;

    // X fragments (k=c consecutive) straight from XT: 16B/lane, 64B/row-chunk
    f16x8 xf[4];
#pragma unroll
    for (int kc = 0; kc < 4; ++kc)
        xf[kc] = *(const f16x8*)(xt + ((size_t)b * NPIX + p_row) * 128 + kc * 32 + quad * 8);

    floatx4 acc[4];
#pragma unroll
    for (int n = 0; n < 4; ++n) acc[n] = floatx4{0.f, 0.f, 0.f, 0.f};

    if (type < 2) {
        // ---- C[p][o]: A = X frag, B = W frag ----
#pragma unroll
        for (int n = 0; n < 4; ++n)
#pragma unroll
            for (int kc = 0; kc < 4; ++kc) {
                f16x8 bf = *(const f16x8*)&wlds[(n * 16 + l16) * 136 + kc * 32 + quad * 8];
                acc[n] = __builtin_amdgcn_mfma_f32_16x16x32_f16(xf[kc], bf, acc[n], 0, 0, 0);
            }
        const float qs = (type == 0) ? 0.17677669529663687f * 1.4426950408889634f : 1.0f;
        f16* dst = (type == 0) ? qh : kh;
#pragma unroll
        for (int n = 0; n < 4; ++n) {
            const int og   = y * 64 + n * 16 + l16;
            const int head = (og >> 5) & 3;
            const int d    = og & 31;
            f16* base = dst + (size_t)(b * 4 + head) * NPIX * 32;
#pragma unroll
            for (int r = 0; r < 4; ++r) {
                const int p = pbase + wave * 16 + quad * 4 + r;
                base[(size_t)p * 32 + d] = (f16)(acc[n][r] * qs);
            }
        }
    } else {
        // ---- C[o][p]: A = W frag, B = X frag ----
#pragma unroll
        for (int m = 0; m < 4; ++m)
#pragma unroll
            for (int kc = 0; kc < 4; ++kc) {
                f16x8 af = *(const f16x8*)&wlds[(m * 16 + l16) * 136 + kc * 32 + quad * 8];
                acc[m] = __builtin_amdgcn_mfma_f32_16x16x32_f16(af, xf[kc], acc[m], 0, 0, 0);
            }
#pragma unroll
        for (int m = 0; m < 4; ++m)
#pragma unroll
            for (int r = 0; r < 4; ++r) {
                const int og   = y * 64 + m * 16 + quad * 4 + r;
                const int head = (og >> 5) & 3;
                const int d    = og & 31;
                vth[((size_t)(b * 4 + head) * 32 + d) * NPIX + p_row] = (f16)acc[m][r];
            }
    }
}

// ---------------------------------------------------------------------------
// Kernel 2: flash attention — v8 form, UNTOUCHED (known-good 60.0 us).
// ---------------------------------------------------------------------------
#define ATTN_STEP(BUF, KF, KFN, TNXT)                                          \
{                                                                              \
    /* prefetch next K tile's fragments (consumed next step) */                \
    if ((TNXT) < NT) {                                                         \
        _Pragma("unroll")                                                      \
        for (int t = 0; t < 8; ++t)                                            \
            KFN[t] = *(const f16x8*)(kp + (size_t)((TNXT) * KT + t * 16) * 32);\
    }                                                                          \
    /* T14: issue next V tile's global loads now, publish after compute */     \
    int4 nv0, nv1;                                                             \
    if ((TNXT) < NT) {                                                         \
        const int4* vs = (const int4*)(vrow + (TNXT) * KT);                    \
        nv0 = vs[vcc]; nv1 = vs[vcc + 1];                                      \
    }                                                                          \
    /* V frags for current tile from LDS */                                    \
    f16x4 vf[8][2];                                                            \
    _Pragma("unroll")                                                          \
    for (int c = 0; c < 8; ++c) {                                              \
        _Pragma("unroll")                                                      \
        for (int dh = 0; dh < 2; ++dh)                                         \
            vf[c][dh] = *(const f16x4*)&vlds[BUF][(dh * 16 + l16) * VROW + c * 16 + quad * 4]; \
    }                                                                          \
    /* S^T for BOTH q-subtiles first (16 MFMA back-to-back) */                 \
    floatx4 st0[8], st1[8];                                                    \
    _Pragma("unroll")                                                          \
    for (int t = 0; t < 8; ++t) {                                              \
        floatx4 z = {0.f, 0.f, 0.f, 0.f};                                      \
        st0[t] = __builtin_amdgcn_mfma_f32_16x16x32_f16(KF[t], qB[0], z, 0, 0, 0); \
    }                                                                          \
    _Pragma("unroll")                                                          \
    for (int t = 0; t < 8; ++t) {                                              \
        floatx4 z = {0.f, 0.f, 0.f, 0.f};                                      \
        st1[t] = __builtin_amdgcn_mfma_f32_16x16x32_f16(KF[t], qB[1], z, 0, 0, 0); \
    }                                                                          \
    /* exp(h0): pkrtz-pack + fdot2 row sums (overlaps tail of QK(h1)) */       \
    f16x4 pf0[8], pf1[8];                                                      \
    float ls0 = 0.f, ls1 = 0.f;                                                \
    _Pragma("unroll")                                                          \
    for (int c = 0; c < 8; ++c) {                                              \
        float e0 = __builtin_amdgcn_exp2f(st0[c][0]);                          \
        float e1 = __builtin_amdgcn_exp2f(st0[c][1]);                          \
        float e2 = __builtin_amdgcn_exp2f(st0[c][2]);                          \
        float e3 = __builtin_amdgcn_exp2f(st0[c][3]);                          \
        pk4 u;                                                                 \
        u.h[0] = __builtin_amdgcn_cvt_pkrtz(e0, e1);                           \
        u.h[1] = __builtin_amdgcn_cvt_pkrtz(e2, e3);                           \
        pf0[c] = u.v;                                                          \
        ls0 = __builtin_amdgcn_fdot2(u.h[0], one2, ls0, false);                \
        ls0 = __builtin_amdgcn_fdot2(u.h[1], one2, ls0, false);                \
    }                                                                          \
    /* PV(h0) MFMAs interleaved with exp(h1) VALU: both pipes busy */          \
    _Pragma("unroll")                                                          \
    for (int c = 0; c < 8; ++c) {                                              \
        oacc[0][0] = __builtin_amdgcn_mfma_f32_16x16x16f16(pf0[c], vf[c][0], oacc[0][0], 0, 0, 0); \
        oacc[0][1] = __builtin_amdgcn_mfma_f32_16x16x16f16(pf0[c], vf[c][1], oacc[0][1], 0, 0, 0); \
        float e0 = __builtin_amdgcn_exp2f(st1[c][0]);                          \
        float e1 = __builtin_amdgcn_exp2f(st1[c][1]);                          \
        float e2 = __builtin_amdgcn_exp2f(st1[c][2]);                          \
        float e3 = __builtin_amdgcn_exp2f(st1[c][3]);                          \
        pk4 u;                                                                 \
        u.h[0] = __builtin_amdgcn_cvt_pkrtz(e0, e1);                           \
        u.h[1] = __builtin_amdgcn_cvt_pkrtz(e2, e3);                           \
        pf1[c] = u.v;                                                          \
        ls1 = __builtin_amdgcn_fdot2(u.h[0], one2, ls1, false);                \
        ls1 = __builtin_amdgcn_fdot2(u.h[1], one2, ls1, false);                \
    }                                                                          \
    lsum[0] += ls0; lsum[1] += ls1;                                            \
    _Pragma("unroll")                                                          \
    for (int c = 0; c < 8; ++c) {                                              \
        oacc[1][0] = __builtin_amdgcn_mfma_f32_16x16x16f16(pf1[c], vf[c][0], oacc[1][0], 0, 0, 0); \
        oacc[1][1] = __builtin_amdgcn_mfma_f32_16x16x16f16(pf1[c], vf[c][1], oacc[1][1], 0, 0, 0); \
    }                                                                          \
    /* publish next V tile into the other buffer (consumed last step) */       \
    if ((TNXT) < NT) {                                                         \
        *(int4*)&vlds[(BUF) ^ 1][voff]     = nv0;                              \
        *(int4*)&vlds[(BUF) ^ 1][voff + 8] = nv1;                              \
    }                                                                          \
    __syncthreads();                                                           \
}

__global__ __launch_bounds__(256, 2) void attn_kernel(
    const f16* __restrict__ qh, const f16* __restrict__ kh,
    const f16* __restrict__ vth, f16* __restrict__ att)
{
    __shared__ f16 vlds[2][32 * VROW];   // 2 x 8.5 KB, padded [d][key]

    const int tid  = threadIdx.x;
    const int wave = tid >> 6;
    const int lane = tid & 63;
    const int quad = lane >> 4;
    const int l16  = lane & 15;
    const int bh   = blockIdx.y;
    const int qbase = blockIdx.x * 128 + wave * 32;

    const f16* kb = kh + (size_t)bh * NPIX * 32;
    const f16* vb = vth + (size_t)bh * 32 * NPIX;
    // per-lane K fragment pointer: row l16 (+t*16), col quad*8 within a tile
    const f16* kp = kb + (size_t)l16 * 32 + quad * 8;

    // V staging geometry: 32 d-rows x 128 keys = 512 int4, 2/thread
    const int vr = tid >> 3, vcc = (tid & 7) * 2;
    const int voff = vr * VROW + vcc * 8;
    const f16* vrow = vb + (size_t)vr * NPIX;

    const h2 one2 = {(__fp16)1.0f, (__fp16)1.0f};

    // Q B-frags (B[k=d][n=q]): two 16-q subtiles
    f16x8 qB[2];
#pragma unroll
    for (int h = 0; h < 2; ++h)
        qB[h] = *(const f16x8*)(qh + ((size_t)bh * NPIX + qbase + h * 16 + l16) * 32 + quad * 8);

    floatx4 oacc[2][2];
#pragma unroll
    for (int h = 0; h < 2; ++h)
#pragma unroll
        for (int dh = 0; dh < 2; ++dh) oacc[h][dh] = floatx4{0.f, 0.f, 0.f, 0.f};
    float lsum[2] = {0.f, 0.f};

    // prologue: V tile 0 -> vlds[0]; K tile 0 frags -> kfA
    f16x8 kfA[8], kfB[8];
    {
        const int4* vs = (const int4*)vrow;
        int4 a = vs[vcc], b2 = vs[vcc + 1];
        *(int4*)&vlds[0][voff]     = a;
        *(int4*)&vlds[0][voff + 8] = b2;
    }
#pragma unroll
    for (int t = 0; t < 8; ++t)
        kfA[t] = *(const f16x8*)(kp + (size_t)(t * 16) * 32);
    __syncthreads();

    for (int it = 0; it < NT / 2; ++it) {
        const int t0 = it * 2;
        ATTN_STEP(0, kfA, kfB, t0 + 1);   // tile t0   (even -> buf 0)
        ATTN_STEP(1, kfB, kfA, t0 + 2);   // tile t0+1 (odd  -> buf 1)
    }

    // epilogue: reduce lsum across quads (q lives in l16), divide, store f16
#pragma unroll
    for (int h = 0; h < 2; ++h) {
        float l = lsum[h];
        l += __shfl_xor(l, 16);
        l += __shfl_xor(l, 32);
        const float inv = 1.0f / l;            // valid per q = l16
#pragma unroll
        for (int r = 0; r < 4; ++r) {
            const float invr = __shfl(inv, quad * 4 + r);   // inv for q-row quad*4+r
            const int q = qbase + h * 16 + quad * 4 + r;
            f16* ob = att + ((size_t)bh * NPIX + q) * 32;
            ob[l16]      = (f16)(oacc[h][0][r] * invr);
            ob[16 + l16] = (f16)(oacc[h][1][r] * invr);
        }
    }
}

// ---------------------------------------------------------------------------
// Kernel 3: output projection as fp16 MFMA GEMM.
// v9: p-split 64 -> 32 per block: grid (128 p-tiles, 4 b) = 512 blocks =
// 2 blocks/CU (was 1) so the serial W-stage and store tail overlap with the
// co-resident block. Full W staged per block (no att-read duplication —
// the known-bad v2 o-split is avoided). Wave w: p-half w&1, m-quad w>>1.
// ---------------------------------------------------------------------------
__global__ __launch_bounds__(256) void proj_mfma(
    const f16* __restrict__ att, const float* __restrict__ wp,
    const float* __restrict__ bp, float* __restrict__ out)
{
    __shared__ f16 wplds[128 * 136];   // [o][c] padded, 34.8 KB
    __shared__ float bplds[128];
    const int tid  = threadIdx.x;
    const int wave = tid >> 6;
    const int lane = tid & 63;
    const int quad = lane >> 4;
    const int l16  = lane & 15;
    const int pbase = blockIdx.x * 32;
    const int b     = blockIdx.y;

    if (tid < 128) bplds[tid] = bp[tid];
#pragma unroll
    for (int i = 0; i < 16; ++i) {
        int idx = i * 256 + tid;               // 4096 float4 = 128*128 floats
        int o = idx >> 5, ch = idx & 31;
        float4 wv = *(const float4*)(wp + (size_t)o * 128 + ch * 4);
        f16x4 h; h[0] = (f16)wv.x; h[1] = (f16)wv.y; h[2] = (f16)wv.z; h[3] = (f16)wv.w;
        *(f16x4*)&wplds[o * 136 + ch * 4] = h;
    }
    __syncthreads();

    const f16* ab = att + (size_t)b * 4 * NPIX * 32;
    const int p_col = pbase + (wave & 1) * 16 + l16;
    const int mbase = (wave >> 1) * 4;
    f16x8 bf[4];
#pragma unroll
    for (int kc = 0; kc < 4; ++kc)
        bf[kc] = *(const f16x8*)(ab + ((size_t)kc * NPIX + p_col) * 32 + quad * 8);

    floatx4 acc[4];
#pragma unroll
    for (int mi = 0; mi < 4; ++mi) acc[mi] = floatx4{0.f, 0.f, 0.f, 0.f};
#pragma unroll
    for (int mi = 0; mi < 4; ++mi)
#pragma unroll
        for (int kc = 0; kc < 4; ++kc) {
            f16x8 af = *(const f16x8*)&wplds[((mbase + mi) * 16 + l16) * 136 + kc * 32 + quad * 8];
            acc[mi] = __builtin_amdgcn_mfma_f32_16x16x32_f16(af, bf[kc], acc[mi], 0, 0, 0);
        }

#pragma unroll
    for (int mi = 0; mi < 4; ++mi)
#pragma unroll
        for (int r = 0; r < 4; ++r) {
            const int o = (mbase + mi) * 16 + quad * 4 + r;
            out[((size_t)b * 128 + o) * NPIX + p_col] = acc[mi][r] + bplds[o];
        }
}

// ---------------------------------------------------------------------------
extern "C" void kernel_launch(void* const* d_in, const int* in_sizes, int n_in,
                              void* d_out, int out_size, void* d_ws, size_t ws_size,
                              hipStream_t stream)
{
    const float* x      = (const float*)d_in[0];
    const float* w_qkv  = (const float*)d_in[1];
    const float* w_proj = (const float*)d_in[2];
    const float* b_proj = (const float*)d_in[3];
    float* out = (float*)d_out;

    char* ws = (char*)d_ws;
    f16* qh  = (f16*)(ws);                // 4 MB [bh][p][32], pre-scaled
    f16* kh  = (f16*)(ws + (4u << 20));   // 4 MB [bh][p][32]
    f16* vth = (f16*)(ws + (8u << 20));   // 4 MB [bh][d][p]
    f16* att = (f16*)(ws + (12u << 20));  // 4 MB [bh][p][32]
    f16* xt  = (f16*)(ws + (12u << 20));  // 4 MB XT [b][p][c] — overlaps att:
                                          // xt consumed by qkv BEFORE attn writes att

    xpose<<<dim3(256, 4, 1), 256, 0, stream>>>(x, xt);
    qkv_mfma<<<dim3(64, 6, 4), 256, 0, stream>>>(xt, w_qkv, qh, kh, vth);
    attn_kernel<<<dim3(32, 16, 1), 256, 0, stream>>>(qh, kh, vth, att);
    proj_mfma<<<dim3(128, 4, 1), 256, 0, stream>>>(att, w_proj, b_proj, out);
}

// Round 10
// 127.688 us; speedup vs baseline: 1.0209x; 1.0209x over previous
//
#include <hip/hip_runtime.h>

typedef _Float16 f16;
typedef unsigned short u16;
typedef __attribute__((ext_vector_type(8))) f16 f16x8;
typedef __attribute__((ext_vector_type(4))) f16 f16x4;
typedef __attribute__((ext_vector_type(4))) float floatx4;
typedef __attribute__((ext_vector_type(2))) __fp16 h2;   // builtin half type

union pk4 { h2 h[2]; f16x4 v; };   // cvt_pkrtz pairs <-> MFMA A-frag

#define NPIX 4096
#define KT   128          // keys per attention tile
#define NT   (NPIX / KT)  // 32 key tiles
#define VROW 136          // padded V LDS row (128 keys + 8) in f16

// ---------------------------------------------------------------------------
// Kernel 1: QKV projection as fp16 MFMA GEMM.  (v8/round-0 form, known-good)
// grid (64 p-tiles, 6 o-tiles of 64, 4 b), block 256 (4 waves).
// ---------------------------------------------------------------------------
__global__ __launch_bounds__(256) void qkv_mfma(
    const float* __restrict__ x, const float* __restrict__ w,
    f16* __restrict__ qh, f16* __restrict__ kh, f16* __restrict__ vth)
{
    __shared__ f16 wlds[64 * 136];     // [o][c] padded (+8) -> conflict-free frags
    const int tid  = threadIdx.x;
    const int wave = tid >> 6;
    const int lane = tid & 63;
    const int quad = lane >> 4;
    const int l16  = lane & 15;
    const int pbase = blockIdx.x * 64;
    const int y     = blockIdx.y;      // o-tile of 64; type = y>>1
    const int b     = blockIdx.z;

#pragma unroll
    for (int i = 0; i < 8; ++i) {
        int idx = i * 256 + tid;               // 2048 float4
        int o = idx >> 5, ch = idx & 31;
        float4 wv = *(const float4*)(w + (size_t)(y * 64 + o) * 128 + ch * 4);
        f16x4 h; h[0] = (f16)wv.x; h[1] = (f16)wv.y; h[2] = (f16)wv.z; h[3] = (f16)wv.w;
        *(f16x4*)&wlds[o * 136 + ch * 4] = h;
    }
    __syncthreads();

    const float* xb = x + (size_t)b * 128 * NPIX;
    const int type = y >> 1;                   // 0=q 1=k 2=v

    if (type < 2) {
        // ---- C[p][o]: A = X^T (global), B = W (LDS) ----
        const int p_row = pbase + wave * 16 + l16;
        f16x8 af[4];
#pragma unroll
        for (int kc = 0; kc < 4; ++kc) {
            const int c0 = kc * 32 + quad * 8;
#pragma unroll
            for (int j = 0; j < 8; ++j)
                af[kc][j] = (f16)xb[(size_t)(c0 + j) * NPIX + p_row];
        }
        floatx4 acc[4];
#pragma unroll
        for (int n = 0; n < 4; ++n) acc[n] = floatx4{0.f, 0.f, 0.f, 0.f};
#pragma unroll
        for (int n = 0; n < 4; ++n)
#pragma unroll
            for (int kc = 0; kc < 4; ++kc) {
                f16x8 bf = *(const f16x8*)&wlds[(n * 16 + l16) * 136 + kc * 32 + quad * 8];
                acc[n] = __builtin_amdgcn_mfma_f32_16x16x32_f16(af[kc], bf, acc[n], 0, 0, 0);
            }
        const float qs = (type == 0) ? 0.17677669529663687f * 1.4426950408889634f : 1.0f;
        f16* dst = (type == 0) ? qh : kh;
#pragma unroll
        for (int n = 0; n < 4; ++n) {
            const int og   = y * 64 + n * 16 + l16;
            const int head = (og >> 5) & 3;
            const int d    = og & 31;
            f16* base = dst + (size_t)(b * 4 + head) * NPIX * 32;
#pragma unroll
            for (int r = 0; r < 4; ++r) {
                const int p = pbase + wave * 16 + quad * 4 + r;
                base[(size_t)p * 32 + d] = (f16)(acc[n][r] * qs);
            }
        }
    } else {
        // ---- C[o][p]: A = W (LDS), B = X (global) ----
        const int p_col = pbase + wave * 16 + l16;
        f16x8 bf[4];
#pragma unroll
        for (int kc = 0; kc < 4; ++kc) {
            const int c0 = kc * 32 + quad * 8;
#pragma unroll
            for (int j = 0; j < 8; ++j)
                bf[kc][j] = (f16)xb[(size_t)(c0 + j) * NPIX + p_col];
        }
        floatx4 acc[4];
#pragma unroll
        for (int m = 0; m < 4; ++m) acc[m] = floatx4{0.f, 0.f, 0.f, 0.f};
#pragma unroll
        for (int m = 0; m < 4; ++m)
#pragma unroll
            for (int kc = 0; kc < 4; ++kc) {
                f16x8 af = *(const f16x8*)&wlds[(m * 16 + l16) * 136 + kc * 32 + quad * 8];
                acc[m] = __builtin_amdgcn_mfma_f32_16x16x32_f16(af, bf[kc], acc[m], 0, 0, 0);
            }
#pragma unroll
        for (int m = 0; m < 4; ++m)
#pragma unroll
            for (int r = 0; r < 4; ++r) {
                const int og   = y * 64 + m * 16 + quad * 4 + r;
                const int head = (og >> 5) & 3;
                const int d    = og & 31;
                vth[((size_t)(b * 4 + head) * 32 + d) * NPIX + p_col] = (f16)acc[m][r];
            }
    }
}

// ---------------------------------------------------------------------------
// Kernel 2: flash attention — v8 body UNTOUCHED; v10 changes ONLY the grid
// mapping for XCD locality: grid (16 bh, 32 qblocks). Linear wg id = y*16+x,
// XCD ~ id%8 = bh%8, so all 32 q-blocks sharing a bh's K/V land on ONE XCD
// whose L2 (4MB) easily holds its 2 bh x 1MB working set. v9 counters showed
// 34.8MB HBM fetch vs 12MB unique = ~3x cross-XCD amplification; this remap
// turns steady-state K loads from HBM-latency into L2-latency.
// ---------------------------------------------------------------------------
#define ATTN_STEP(BUF, KF, KFN, TNXT)                                          \
{                                                                              \
    /* prefetch next K tile's fragments (consumed next step) */                \
    if ((TNXT) < NT) {                                                         \
        _Pragma("unroll")                                                      \
        for (int t = 0; t < 8; ++t)                                            \
            KFN[t] = *(const f16x8*)(kp + (size_t)((TNXT) * KT + t * 16) * 32);\
    }                                                                          \
    /* T14: issue next V tile's global loads now, publish after compute */     \
    int4 nv0, nv1;                                                             \
    if ((TNXT) < NT) {                                                         \
        const int4* vs = (const int4*)(vrow + (TNXT) * KT);                    \
        nv0 = vs[vcc]; nv1 = vs[vcc + 1];                                      \
    }                                                                          \
    /* V frags for current tile from LDS */                                    \
    f16x4 vf[8][2];                                                            \
    _Pragma("unroll")                                                          \
    for (int c = 0; c < 8; ++c) {                                              \
        _Pragma("unroll")                                                      \
        for (int dh = 0; dh < 2; ++dh)                                         \
            vf[c][dh] = *(const f16x4*)&vlds[BUF][(dh * 16 + l16) * VROW + c * 16 + quad * 4]; \
    }                                                                          \
    /* S^T for BOTH q-subtiles first (16 MFMA back-to-back) */                 \
    floatx4 st0[8], st1[8];                                                    \
    _Pragma("unroll")                                                          \
    for (int t = 0; t < 8; ++t) {                                              \
        floatx4 z = {0.f, 0.f, 0.f, 0.f};                                      \
        st0[t] = __builtin_amdgcn_mfma_f32_16x16x32_f16(KF[t], qB[0], z, 0, 0, 0); \
    }                                                                          \
    _Pragma("unroll")                                                          \
    for (int t = 0; t < 8; ++t) {                                              \
        floatx4 z = {0.f, 0.f, 0.f, 0.f};                                      \
        st1[t] = __builtin_amdgcn_mfma_f32_16x16x32_f16(KF[t], qB[1], z, 0, 0, 0); \
    }                                                                          \
    /* exp(h0): pkrtz-pack + fdot2 row sums (overlaps tail of QK(h1)) */       \
    f16x4 pf0[8], pf1[8];                                                      \
    float ls0 = 0.f, ls1 = 0.f;                                                \
    _Pragma("unroll")                                                          \
    for (int c = 0; c < 8; ++c) {                                              \
        float e0 = __builtin_amdgcn_exp2f(st0[c][0]);                          \
        float e1 = __builtin_amdgcn_exp2f(st0[c][1]);                          \
        float e2 = __builtin_amdgcn_exp2f(st0[c][2]);                          \
        float e3 = __builtin_amdgcn_exp2f(st0[c][3]);                          \
        pk4 u;                                                                 \
        u.h[0] = __builtin_amdgcn_cvt_pkrtz(e0, e1);                           \
        u.h[1] = __builtin_amdgcn_cvt_pkrtz(e2, e3);                           \
        pf0[c] = u.v;                                                          \
        ls0 = __builtin_amdgcn_fdot2(u.h[0], one2, ls0, false);                \
        ls0 = __builtin_amdgcn_fdot2(u.h[1], one2, ls0, false);                \
    }                                                                          \
    /* PV(h0) MFMAs interleaved with exp(h1) VALU: both pipes busy */          \
    _Pragma("unroll")                                                          \
    for (int c = 0; c < 8; ++c) {                                              \
        oacc[0][0] = __builtin_amdgcn_mfma_f32_16x16x16f16(pf0[c], vf[c][0], oacc[0][0], 0, 0, 0); \
        oacc[0][1] = __builtin_amdgcn_mfma_f32_16x16x16f16(pf0[c], vf[c][1], oacc[0][1], 0, 0, 0); \
        float e0 = __builtin_amdgcn_exp2f(st1[c][0]);                          \
        float e1 = __builtin_amdgcn_exp2f(st1[c][1]);                          \
        float e2 = __builtin_amdgcn_exp2f(st1[c][2]);                          \
        float e3 = __builtin_amdgcn_exp2f(st1[c][3]);                          \
        pk4 u;                                                                 \
        u.h[0] = __builtin_amdgcn_cvt_pkrtz(e0, e1);                           \
        u.h[1] = __builtin_amdgcn_cvt_pkrtz(e2, e3);                           \
        pf1[c] = u.v;                                                          \
        ls1 = __builtin_amdgcn_fdot2(u.h[0], one2, ls1, false);                \
        ls1 = __builtin_amdgcn_fdot2(u.h[1], one2, ls1, false);                \
    }                                                                          \
    lsum[0] += ls0; lsum[1] += ls1;                                            \
    _Pragma("unroll")                                                          \
    for (int c = 0; c < 8; ++c) {                                              \
        oacc[1][0] = __builtin_amdgcn_mfma_f32_16x16x16f16(pf1[c], vf[c][0], oacc[1][0], 0, 0, 0); \
        oacc[1][1] = __builtin_amdgcn_mfma_f32_16x16x16f16(pf1[c], vf[c][1], oacc[1][1], 0, 0, 0); \
    }                                                                          \
    /* publish next V tile into the other buffer (consumed last step) */       \
    if ((TNXT) < NT) {                                                         \
        *(int4*)&vlds[(BUF) ^ 1][voff]     = nv0;                              \
        *(int4*)&vlds[(BUF) ^ 1][voff + 8] = nv1;                              \
    }                                                                          \
    __syncthreads();                                                           \
}

__global__ __launch_bounds__(256, 2) void attn_kernel(
    const f16* __restrict__ qh, const f16* __restrict__ kh,
    const f16* __restrict__ vth, f16* __restrict__ att)
{
    __shared__ f16 vlds[2][32 * VROW];   // 2 x 8.5 KB, padded [d][key]

    const int tid  = threadIdx.x;
    const int wave = tid >> 6;
    const int lane = tid & 63;
    const int quad = lane >> 4;
    const int l16  = lane & 15;
    const int bh   = blockIdx.x;                       // v10: bh on X (XCD-local)
    const int qbase = blockIdx.y * 128 + wave * 32;    // v10: q-block on Y

    const f16* kb = kh + (size_t)bh * NPIX * 32;
    const f16* vb = vth + (size_t)bh * 32 * NPIX;
    // per-lane K fragment pointer: row l16 (+t*16), col quad*8 within a tile
    const f16* kp = kb + (size_t)l16 * 32 + quad * 8;

    // V staging geometry: 32 d-rows x 128 keys = 512 int4, 2/thread
    const int vr = tid >> 3, vcc = (tid & 7) * 2;
    const int voff = vr * VROW + vcc * 8;
    const f16* vrow = vb + (size_t)vr * NPIX;

    const h2 one2 = {(__fp16)1.0f, (__fp16)1.0f};

    // Q B-frags (B[k=d][n=q]): two 16-q subtiles
    f16x8 qB[2];
#pragma unroll
    for (int h = 0; h < 2; ++h)
        qB[h] = *(const f16x8*)(qh + ((size_t)bh * NPIX + qbase + h * 16 + l16) * 32 + quad * 8);

    floatx4 oacc[2][2];
#pragma unroll
    for (int h = 0; h < 2; ++h)
#pragma unroll
        for (int dh = 0; dh < 2; ++dh) oacc[h][dh] = floatx4{0.f, 0.f, 0.f, 0.f};
    float lsum[2] = {0.f, 0.f};

    // prologue: V tile 0 -> vlds[0]; K tile 0 frags -> kfA
    f16x8 kfA[8], kfB[8];
    {
        const int4* vs = (const int4*)vrow;
        int4 a = vs[vcc], b2 = vs[vcc + 1];
        *(int4*)&vlds[0][voff]     = a;
        *(int4*)&vlds[0][voff + 8] = b2;
    }
#pragma unroll
    for (int t = 0; t < 8; ++t)
        kfA[t] = *(const f16x8*)(kp + (size_t)(t * 16) * 32);
    __syncthreads();

    for (int it = 0; it < NT / 2; ++it) {
        const int t0 = it * 2;
        ATTN_STEP(0, kfA, kfB, t0 + 1);   // tile t0   (even -> buf 0)
        ATTN_STEP(1, kfB, kfA, t0 + 2);   // tile t0+1 (odd  -> buf 1)
    }

    // epilogue: reduce lsum across quads (q lives in l16), divide, store f16
#pragma unroll
    for (int h = 0; h < 2; ++h) {
        float l = lsum[h];
        l += __shfl_xor(l, 16);
        l += __shfl_xor(l, 32);
        const float inv = 1.0f / l;            // valid per q = l16
#pragma unroll
        for (int r = 0; r < 4; ++r) {
            const float invr = __shfl(inv, quad * 4 + r);   // inv for q-row quad*4+r
            const int q = qbase + h * 16 + quad * 4 + r;
            f16* ob = att + ((size_t)bh * NPIX + q) * 32;
            ob[l16]      = (f16)(oacc[h][0][r] * invr);
            ob[16 + l16] = (f16)(oacc[h][1][r] * invr);
        }
    }
}

// ---------------------------------------------------------------------------
// Kernel 3: output projection as fp16 MFMA GEMM.
// v10: att staged through LDS. The old bf load was a 16-segment scatter
// (16B/lane at 64B stride — v4's V-read pathology). att[bh][p][32] is 4KB
// CONTIGUOUS per (bh, 64-p tile): staged as 4 fully-coalesced int4/thread
// into alds[p][c] (c = head*32+d, padded row 136), frags via ds_read_b128
// (2-way bank alias = free). Grid stays (64,4)=256 — both split variants
// measured -4us (v2 o-split, v9 p-split).
// ---------------------------------------------------------------------------
__global__ __launch_bounds__(256) void proj_mfma(
    const f16* __restrict__ att, const float* __restrict__ wp,
    const float* __restrict__ bp, float* __restrict__ out)
{
    __shared__ f16 wplds[128 * 136];   // [o][c] padded, 34.8 KB
    __shared__ f16 alds[64 * 136];     // [p][c] padded, 17.4 KB
    __shared__ float bplds[128];
    const int tid  = threadIdx.x;
    const int wave = tid >> 6;
    const int lane = tid & 63;
    const int quad = lane >> 4;
    const int l16  = lane & 15;
    const int pbase = blockIdx.x * 64;
    const int b     = blockIdx.y;

    if (tid < 128) bplds[tid] = bp[tid];
#pragma unroll
    for (int i = 0; i < 16; ++i) {
        int idx = i * 256 + tid;               // 4096 float4 = 128*128 floats
        int o = idx >> 5, ch = idx & 31;
        float4 wv = *(const float4*)(wp + (size_t)o * 128 + ch * 4);
        f16x4 h; h[0] = (f16)wv.x; h[1] = (f16)wv.y; h[2] = (f16)wv.z; h[3] = (f16)wv.w;
        *(f16x4*)&wplds[o * 136 + ch * 4] = h;
    }
    // stage att tile: per head, 64p x 32d = 4KB contiguous = 256 int4.
    // i = head (all 256 threads cooperate on one head per iteration).
    const f16* ab = att + (size_t)b * 4 * NPIX * 32;
#pragma unroll
    for (int i = 0; i < 4; ++i) {
        const int p = tid >> 2, d8 = (tid & 3) * 8;
        int4 v = *(const int4*)(ab + ((size_t)i * NPIX + pbase + p) * 32 + d8);
        *(int4*)&alds[p * 136 + i * 32 + d8] = v;
    }
    __syncthreads();

    const int p_col = pbase + wave * 16 + l16;
    f16x8 bf[4];
#pragma unroll
    for (int kc = 0; kc < 4; ++kc)
        bf[kc] = *(const f16x8*)&alds[(wave * 16 + l16) * 136 + kc * 32 + quad * 8];

    floatx4 acc[8];
#pragma unroll
    for (int m = 0; m < 8; ++m) acc[m] = floatx4{0.f, 0.f, 0.f, 0.f};
#pragma unroll
    for (int m = 0; m < 8; ++m)
#pragma unroll
        for (int kc = 0; kc < 4; ++kc) {
            f16x8 af = *(const f16x8*)&wplds[(m * 16 + l16) * 136 + kc * 32 + quad * 8];
            acc[m] = __builtin_amdgcn_mfma_f32_16x16x32_f16(af, bf[kc], acc[m], 0, 0, 0);
        }

#pragma unroll
    for (int m = 0; m < 8; ++m)
#pragma unroll
        for (int r = 0; r < 4; ++r) {
            const int o = m * 16 + quad * 4 + r;
            out[((size_t)b * 128 + o) * NPIX + p_col] = acc[m][r] + bplds[o];
        }
}

// ---------------------------------------------------------------------------
extern "C" void kernel_launch(void* const* d_in, const int* in_sizes, int n_in,
                              void* d_out, int out_size, void* d_ws, size_t ws_size,
                              hipStream_t stream)
{
    const float* x      = (const float*)d_in[0];
    const float* w_qkv  = (const float*)d_in[1];
    const float* w_proj = (const float*)d_in[2];
    const float* b_proj = (const float*)d_in[3];
    float* out = (float*)d_out;

    char* ws = (char*)d_ws;
    f16* qh  = (f16*)(ws);                // 4 MB [bh][p][32], pre-scaled
    f16* kh  = (f16*)(ws + (4u << 20));   // 4 MB [bh][p][32]
    f16* vth = (f16*)(ws + (8u << 20));   // 4 MB [bh][d][p]
    f16* att = (f16*)(ws + (12u << 20));  // 4 MB [bh][p][32]

    qkv_mfma<<<dim3(64, 6, 4), 256, 0, stream>>>(x, w_qkv, qh, kh, vth);
    attn_kernel<<<dim3(16, 32, 1), 256, 0, stream>>>(qh, kh, vth, att);
    proj_mfma<<<dim3(64, 4, 1), 256, 0, stream>>>(att, w_proj, b_proj, out);
}